// Round 17
// baseline (539.129 us; speedup 1.0000x reference)
//
#include <hip/hip_runtime.h>
#include <hip/hip_bf16.h>

#define NN 8192
#define CH 256

typedef float f32x4 __attribute__((ext_vector_type(4)));
typedef __bf16 bf16x8 __attribute__((ext_vector_type(8)));

union FragU { uint4 u; bf16x8 h; };

static __device__ __forceinline__ unsigned short f2bf(float f) {
  union { float f; unsigned int u; } v; v.f = f;
  unsigned int x = v.u;
  return (unsigned short)((x + 0x7fffu + ((x >> 16) & 1u)) >> 16);  // RNE
}

static __device__ __forceinline__ unsigned int cvtpk(float a, float b) {
  unsigned int r;  // lo16 = bf16(a), hi16 = bf16(b), RNE
  asm("v_cvt_pk_bf16_f32 %0, %1, %2" : "=v"(r) : "v"(a), "v"(b));
  return r;
}

#if defined(__has_builtin)
#if __has_builtin(__builtin_nontemporal_load)
#define HAVE_NT 1
#endif
#endif

#define WAITV(n) asm volatile("s_waitcnt vmcnt(" #n ")" ::: "memory")
#define LGKM0()  asm volatile("s_waitcnt lgkmcnt(0)" ::: "memory")
#define BARRIER() __builtin_amdgcn_s_barrier()
#define FENCE()  asm volatile("" ::: "memory")

// ---------------- kernel 1: HT[j][k] = bf16(d[k]*H[k][j]), WT[j][c] = bf16(W[c][j])
__global__ __launch_bounds__(256) void k_prep(const float* __restrict__ Hm,
                                              const float* __restrict__ Dm,
                                              const float* __restrict__ Wm,
                                              unsigned short* __restrict__ HT,
                                              unsigned short* __restrict__ WT) {
  __shared__ float tile[64][65];
  int bx = blockIdx.x, t = threadIdx.x;
  bool isH = bx < 512;
  int b = isH ? bx : bx - 512;
  int r0 = (b >> 2) * 64;
  int j0 = (b & 3) * 64;
  const float* src = isH ? Hm : Wm;

  int r = t >> 2;
  int cq = (t & 3) * 16;
  float dval = isH ? rsqrtf(Dm[(size_t)(r0 + r) * (NN + 1)]) : 1.0f;
  const float* p = src + (size_t)(r0 + r) * CH + j0 + cq;
#pragma unroll
  for (int u = 0; u < 4; ++u) {
    float4 v = *(const float4*)(p + u * 4);
    tile[r][cq + u * 4 + 0] = v.x * dval;
    tile[r][cq + u * 4 + 1] = v.y * dval;
    tile[r][cq + u * 4 + 2] = v.z * dval;
    tile[r][cq + u * 4 + 3] = v.w * dval;
  }
  __syncthreads();
  int j = t >> 2;
  int kq = (t & 3) * 16;
  __align__(16) unsigned short ov[16];
#pragma unroll
  for (int i = 0; i < 16; ++i) ov[i] = f2bf(tile[kq + i][j]);
  unsigned short* dst = isH ? (HT + (size_t)(j0 + j) * NN + r0 + kq)
                            : (WT + (size_t)(j0 + j) * CH + r0 + kq);
  *(uint4*)dst = *(uint4*)ov;
  *(uint4*)(dst + 8) = *(uint4*)(ov + 8);
}

// ---------------- fused kernel: out = diag(d) * (bf16(A) @ HT^T) @ W
// BM=32, BN=256, grid 256 x 512 threads.
// Round-14 post-mortem: B path is LATENCY-bound, not BW-bound. Little's law:
// old steady state had ~6 VMEM ops (~96 B) in flight per wave; measured B
// throughput 9.5 B/cyc/CU implies ~80-100 cyc service latency (L2 hits) with
// the queue as the limiter. nt-residency fix was therefore near-null (-15 us).
// Round-14 change: B prefetch depth 1 -> 3 tiles (4 rotating reg sets bb0..3,
// statically indexed via 4-tile loop unroll), A stays depth-2 by parity.
// Steady state: 14 VMEM ops in flight (B(k)x4 .. B(k+2)x4 + A(k+1),A(k+2));
// ONE WAITV(9) per tile retires exactly [B(k)x4, A(k+1)]. Quad-buffered LDS,
// one barrier per tile (write buf (k+1)&3 vs read buf (k-1)&3 in each epoch:
// distance 2 mod 4 -> race-free). Tail peeled (waits 9/9/4/0).
__global__ __launch_bounds__(512, 1) void k_fused(const float* __restrict__ A,
                                                  const float* __restrict__ Dm,
                                                  const unsigned short* __restrict__ HT,
                                                  const unsigned short* __restrict__ WT,
                                                  float* __restrict__ out) {
  constexpr int NIT = NN / 64;              // 128 K-tiles
  __shared__ unsigned short Asb[4][2048];   // 4 bufs x [32 rows][64 halfs] bf16, swizzled
  __shared__ unsigned short Gs[32][264];
  __shared__ float dsh[32];
  const int t = threadIdx.x, l = t & 63, w = t >> 6;
  const int lan = l & 15, quad = l >> 4;
  const int i0 = blockIdx.x * 32;

  const int arow = t >> 4;  // staging row 0..31
  const int aswr = arow * 64 + (((t & 15) * 4) ^ ((arow & 7) * 8));  // swizzled half idx
  const char* Ag = (const char*)A + (size_t)(i0 + arow) * NN * 4 + (t & 15) * 16;
  const unsigned short* Bb = HT + (size_t)(w * 32 + lan) * NN + quad * 8;

  if (t < 32) dsh[t] = rsqrtf(Dm[(size_t)(i0 + t) * (NN + 1)]);

  FragU bb0[4], bb1[4], bb2[4], bb3[4];
  f32x4 aS0, aS1;           // A staging reg sets: A(j) lives in set (j&1)
  f32x4 acc[2][2];
#pragma unroll
  for (int mt = 0; mt < 2; ++mt)
#pragma unroll
    for (int nt = 0; nt < 2; ++nt)
#pragma unroll
      for (int c = 0; c < 4; ++c) acc[mt][nt][c] = 0.0f;

  auto aload = [&](f32x4& dst, int kt) {
#ifdef HAVE_NT
    dst = __builtin_nontemporal_load((const f32x4*)(Ag + (size_t)kt * 256));
#else
    dst = *(const f32x4*)(Ag + (size_t)kt * 256);
#endif
  };
  auto cvtwrite = [&](const f32x4& v, int bi) {
    uint2 pk;
    pk.x = cvtpk(v[0], v[1]);
    pk.y = cvtpk(v[2], v[3]);
    *(uint2*)&Asb[bi][aswr] = pk;
  };
  auto loadB = [&](FragU (&dst)[4], int kt) {
    const unsigned short* p = Bb + (size_t)kt * 64;
#pragma unroll
    for (int ss = 0; ss < 2; ++ss)
#pragma unroll
      for (int nt = 0; nt < 2; ++nt)
        dst[ss * 2 + nt].u = *(const uint4*)(p + (size_t)nt * 16 * NN + ss * 32);
  };
  auto compute = [&](FragU (&b)[4], const unsigned short* Ab) {
#pragma unroll
    for (int ss = 0; ss < 2; ++ss) {
      FragU af[2];
#pragma unroll
      for (int mt = 0; mt < 2; ++mt) {
        const int row = mt * 16 + lan;
        af[mt].u = *(const uint4*)&Ab[row * 64 + ((ss * 32 + quad * 8) ^ ((lan & 7) * 8))];
      }
#pragma unroll
      for (int mt = 0; mt < 2; ++mt)
#pragma unroll
        for (int nt = 0; nt < 2; ++nt)
          acc[mt][nt] = __builtin_amdgcn_mfma_f32_16x16x32_bf16(af[mt].h, b[ss * 2 + nt].h,
                                                                acc[mt][nt], 0, 0, 0);
    }
  };

  // TILE(k): WAITV(9) -> [B(k)x4, A(k+1)] retired; cvtwrite A(k+1)->buf(k+1)&3;
  // issue A(k+3)->aS[(k+1)&1], B(k+3)->bb[(k+3)&3]; barrier; compute(bb[k&3], buf k&3).

  // prologue: build 14-deep queue [A1, B0x4, A2, B1x4, B2x4]; buf0 written.
  aload(aS0, 0);
  aload(aS1, 1);
  loadB(bb0, 0);
  WAITV(5);             // retire A(0)
  cvtwrite(aS0, 0);
  aload(aS0, 2);
  loadB(bb1, 1);
  loadB(bb2, 2);

#pragma unroll 1
  for (int kt = 0; kt < NIT - 4; kt += 4) {
    // tile kt (k&3==0): consume bb0/buf0; A(k+1) in aS1; issue A(k+3)->aS1, B(k+3)->bb3
    WAITV(9);
    cvtwrite(aS1, (kt + 1) & 3);
    aload(aS1, kt + 3);
    loadB(bb3, kt + 3);
    LGKM0(); BARRIER(); FENCE();
    compute(bb0, &Asb[kt & 3][0]);
    // tile kt+1 (k&3==1): consume bb1/buf1; A(k+1) in aS0; issue ->aS0, ->bb0
    WAITV(9);
    cvtwrite(aS0, (kt + 2) & 3);
    aload(aS0, kt + 4);
    loadB(bb0, kt + 4);
    LGKM0(); BARRIER(); FENCE();
    compute(bb1, &Asb[(kt + 1) & 3][0]);
    // tile kt+2 (k&3==2): consume bb2/buf2; A(k+1) in aS1; issue ->aS1, ->bb1
    WAITV(9);
    cvtwrite(aS1, (kt + 3) & 3);
    aload(aS1, kt + 5);
    loadB(bb1, kt + 5);
    LGKM0(); BARRIER(); FENCE();
    compute(bb2, &Asb[(kt + 2) & 3][0]);
    // tile kt+3 (k&3==3): consume bb3/buf3; A(k+1) in aS0; issue ->aS0, ->bb2
    WAITV(9);
    cvtwrite(aS0, (kt + 4) & 3);
    aload(aS0, kt + 6);
    loadB(bb2, kt + 6);
    LGKM0(); BARRIER(); FENCE();
    compute(bb3, &Asb[(kt + 3) & 3][0]);
  }

  // peeled tail: tiles 124..127 (queue at entry: [B124x4,A125,B125x4,A126,B126x4])
  {
    // tile 124 (k&3==0): last issues A(127)->aS1, B(127)->bb3
    WAITV(9);
    cvtwrite(aS1, 1);                    // A(125) -> buf1
    aload(aS1, NIT - 1);                 // A(127)
    loadB(bb3, NIT - 1);                 // B(127)
    LGKM0(); BARRIER(); FENCE();
    compute(bb0, &Asb[0][0]);
    // tile 125: retire [B125x4, A126]; no issues
    WAITV(9);
    cvtwrite(aS0, 2);                    // A(126) -> buf2
    LGKM0(); BARRIER(); FENCE();
    compute(bb1, &Asb[1][0]);
    // tile 126: retire [B126x4, A127] -> 4 remain (B127x4)
    WAITV(4);
    cvtwrite(aS1, 3);                    // A(127) -> buf3
    LGKM0(); BARRIER(); FENCE();
    compute(bb2, &Asb[2][0]);
    // tile 127
    WAITV(0);
    LGKM0(); BARRIER(); FENCE();
    compute(bb3, &Asb[3][0]);
  }

  // epilogue: G = d[i] * acc -> bf16 LDS, then out[32][256] = G @ W (via WT)
  LGKM0(); BARRIER(); FENCE();
#pragma unroll
  for (int mt = 0; mt < 2; ++mt)
#pragma unroll
    for (int nt = 0; nt < 2; ++nt)
#pragma unroll
      for (int r = 0; r < 4; ++r) {
        const int row = mt * 16 + quad * 4 + r;
        Gs[row][w * 32 + nt * 16 + lan] = f2bf(acc[mt][nt][r] * dsh[row]);
      }
  __syncthreads();

  const int r0w = (w & 1) * 16, j0c = (w >> 1) * 64;
  f32x4 o[4];
#pragma unroll
  for (int nt = 0; nt < 4; ++nt)
#pragma unroll
    for (int c = 0; c < 4; ++c) o[nt][c] = 0.0f;
#pragma unroll
  for (int ks = 0; ks < 8; ++ks) {
    FragU af;
    af.u = *(const uint4*)&Gs[r0w + lan][ks * 32 + quad * 8];
#pragma unroll
    for (int nt = 0; nt < 4; ++nt) {
      FragU bw;
      bw.u = *(const uint4*)&WT[(size_t)(j0c + nt * 16 + lan) * CH + ks * 32 + quad * 8];
      o[nt] = __builtin_amdgcn_mfma_f32_16x16x32_bf16(af.h, bw.h, o[nt], 0, 0, 0);
    }
  }
#pragma unroll
  for (int nt = 0; nt < 4; ++nt)
#pragma unroll
    for (int r = 0; r < 4; ++r)
      out[(size_t)(i0 + r0w + quad * 4 + r) * CH + j0c + nt * 16 + lan] = o[nt][r];
}

extern "C" void kernel_launch(void* const* d_in, const int* in_sizes, int n_in,
                              void* d_out, int out_size, void* d_ws, size_t ws_size,
                              hipStream_t stream) {
  const float* A  = (const float*)d_in[0];
  const float* Dm = (const float*)d_in[1];
  const float* Hm = (const float*)d_in[2];
  const float* Wm = (const float*)d_in[3];
  float* out = (float*)d_out;
  char* ws = (char*)d_ws;
  unsigned short* HT = (unsigned short*)ws;                       // 4 MiB
  unsigned short* WT = (unsigned short*)(ws + (size_t)4194304);   // 128 KiB

  hipLaunchKernelGGL(k_prep, dim3(528), dim3(256), 0, stream, Hm, Dm, Wm, HT, WT);
  hipLaunchKernelGGL(k_fused, dim3(256), dim3(512), 0, stream, A, Dm, HT, WT, out);
}